// Round 4
// baseline (175.355 us; speedup 1.0000x reference)
//
#include <hip/hip_runtime.h>

// Ordered bi-bi mechanism dydt. Species: [E, EA, EQ, EAB, A, B, P, Q].
// Two lanes per element: lane pair (2j, 2j+1) holds the two float4 halves of
// element j's y-row => every global access is unit-stride float4 across the
// wave. Halves + rates exchanged via __shfl_xor(.,1).
//
// PERSISTENT grid (2048 blocks = 8 blocks/CU x 4 waves = 32 waves/CU resident
// for the whole kernel) + software-pipelined grid-stride loop: prefetch row
// t+T while computing/storing row t. Prior rounds showed one-shot grids spend
// a large fraction of the kernel in ramp/drain at partial occupancy
// (OccupancyPercent 60%) with each wave idle-waiting on a single load batch;
// this keeps every SIMD at 8 waves with loads always in flight, steady-state
// for the entire dispatch.
//
// Lane-pair path safety: T (grid stride) and n2 are both even, so the loop
// predicate (t < n2) always agrees within a lane pair => the __shfl_xor(.,1)
// partner is active whenever this lane is.
//
// (Round 3 resubmission: Round-3 bench was an infra failure — "container
// failed twice" — with no counters; the experiment itself is unchanged.)

__device__ __forceinline__ float4 shfl_xor1(float4 v) {
    float4 r;
    r.x = __shfl_xor(v.x, 1);
    r.y = __shfl_xor(v.y, 1);
    r.z = __shfl_xor(v.z, 1);
    r.w = __shfl_xor(v.w, 1);
    return r;
}

__device__ __forceinline__ float4 ode_compute(float4 q, float4 mine, int h) {
    // exchange y-halves with neighbor lane
    float4 p = shfl_xor1(q);
    float4 ya = h ? p : q;    // E, EA, EQ, EAB
    float4 yb = h ? q : p;    // A, B, P, Q

    // exchange rates (even lane loaded kf, odd lane loaded kr)
    float4 other = shfl_xor1(mine);
    float4 f = h ? other : mine;   // kf0..kf3
    float4 r = h ? mine : other;   // kr0..kr3

    float E  = ya.x, EA = ya.y, EQ = ya.z, EAB = ya.w;
    float A  = yb.x, Bc = yb.y, P  = yb.z, Q   = yb.w;

    float v0 = f.x * E   * A  - r.x * EA;
    float v1 = f.y * EA  * Bc - r.y * EAB;
    float v2 = f.z * EAB      - r.z * EQ * P;
    float v3 = f.w * EQ       - r.w * E  * Q;

    float4 o;
    if (h == 0) {
        o.x = v3 - v0;   // dE
        o.y = v0 - v1;   // dEA
        o.z = v2 - v3;   // dEQ
        o.w = v1 - v2;   // dEAB
    } else {
        o.x = -v0;       // dA
        o.y = -v1;       // dB
        o.z =  v2;       // dP
        o.w =  v3;       // dQ
    }
    return o;
}

__global__ __launch_bounds__(256, 8) void ode_kernel(
    const float4* __restrict__ y4,
    const float4* __restrict__ kf4,
    const float4* __restrict__ kr4,
    float4* __restrict__ out4,
    int n2)   // n2 = 2*B (total float4 rows of y)
{
    const int T  = gridDim.x * blockDim.x;                // grid stride (even)
    int t = blockIdx.x * blockDim.x + threadIdx.x;
    const int h = t & 1;

    // even lane reads forward rates, odd lane reverse rates
    const float4* __restrict__ rp = h ? kr4 : kf4;

    // ---- software pipeline: prologue load ----
    bool v = t < n2;
    float4 q, m;
    if (v) {
        q = y4[t];         // unit-stride float4 across wave
        m = rp[t >> 1];    // unit-stride float4 across lane pairs
    }

    while (v) {
        // prefetch next grid-stride row while current one computes
        int  tn = t + T;
        bool vn = tn < n2;
        float4 qn, mn;
        if (vn) {
            qn = y4[tn];
            mn = rp[tn >> 1];
        }

        float4 o = ode_compute(q, m, h);
        out4[t] = o;

        t = tn; v = vn; q = qn; m = mn;
    }
}

extern "C" void kernel_launch(void* const* d_in, const int* in_sizes, int n_in,
                              void* d_out, int out_size, void* d_ws, size_t ws_size,
                              hipStream_t stream) {
    // inputs: [0]=t (1,), [1]=y (B,8), [2]=forward_rates (B,4), [3]=reverse_rates (B,4)
    const float4* y4  = (const float4*)d_in[1];
    const float4* kf4 = (const float4*)d_in[2];
    const float4* kr4 = (const float4*)d_in[3];
    float4* out4 = (float4*)d_out;
    int B  = in_sizes[1] / 8;
    int n2 = 2 * B;

    // Persistent grid: 8 blocks/CU x 256 CUs -> 32 waves/CU resident
    // throughout (VGPR<=32 permits 8 waves/SIMD).
    int block = 256;
    int grid  = 2048;
    int maxg  = (n2 + block - 1) / block;
    if (grid > maxg) grid = maxg;
    ode_kernel<<<grid, block, 0, stream>>>(y4, kf4, kr4, out4, n2);
}

// Round 5
// 168.312 us; speedup vs baseline: 1.0418x; 1.0418x over previous
//
#include <hip/hip_runtime.h>

// Ordered bi-bi mechanism dydt. Species: [E, EA, EQ, EAB, A, B, P, Q].
//
// This revision: ONE THREAD PER ELEMENT, no cross-lane exchange at all.
// Thread e loads y4[2e], y4[2e+1], kf4[e], kr4[e] (64B), computes the four
// net rates locally, stores out4[2e], out4[2e+1] (32B). This removes the 8
// ds_swizzle ops + vmcnt->lgkmcnt serialized chain per row that every prior
// variant shared (the one subsystem no counter could exonerate: gfx950 has
// no VMEM/LDS-wait PMC, and 4 structurally different exchange-based kernels
// all measured 59-66us with every visible pipe idle).
// Lane addresses stride 32B, so each load instruction half-uses its cache
// lines; the sibling instruction picks up the other half via L1 — no extra
// HBM traffic. ITERS=2 batched loads-first => 128B in flight per thread.
// NT hints: pure streaming, don't contend for L2 retention.

typedef float v4f __attribute__((ext_vector_type(4)));

#define ITERS 2

__device__ __forceinline__ void ode_elem(v4f ya, v4f yb, v4f f, v4f r,
                                         v4f& oa, v4f& ob) {
    float E  = ya.x, EA = ya.y, EQ = ya.z, EAB = ya.w;
    float A  = yb.x, Bc = yb.y, P  = yb.z, Q   = yb.w;

    float v0 = f.x * E   * A  - r.x * EA;
    float v1 = f.y * EA  * Bc - r.y * EAB;
    float v2 = f.z * EAB      - r.z * EQ * P;
    float v3 = f.w * EQ       - r.w * E  * Q;

    oa.x = v3 - v0;   // dE
    oa.y = v0 - v1;   // dEA
    oa.z = v2 - v3;   // dEQ
    oa.w = v1 - v2;   // dEAB
    ob.x = -v0;       // dA
    ob.y = -v1;       // dB
    ob.z =  v2;       // dP
    ob.w =  v3;       // dQ
}

__global__ __launch_bounds__(256) void ode_kernel(
    const v4f* __restrict__ y4,
    const v4f* __restrict__ kf4,
    const v4f* __restrict__ kr4,
    v4f* __restrict__ out4,
    int B)    // number of elements
{
    const int stride = gridDim.x * blockDim.x;
    const int e0 = blockIdx.x * blockDim.x + threadIdx.x;

    if (e0 + (ITERS - 1) * stride < B) {
        // ---- fast path: branch-free. all loads -> compute -> all stores ----
        v4f ya[ITERS], yb[ITERS], f[ITERS], r[ITERS];
        #pragma unroll
        for (int k = 0; k < ITERS; ++k) {
            int e = e0 + k * stride;
            ya[k] = __builtin_nontemporal_load(y4 + 2 * e);
            yb[k] = __builtin_nontemporal_load(y4 + 2 * e + 1);
            f[k]  = __builtin_nontemporal_load(kf4 + e);
            r[k]  = __builtin_nontemporal_load(kr4 + e);
        }

        v4f oa[ITERS], ob[ITERS];
        #pragma unroll
        for (int k = 0; k < ITERS; ++k)
            ode_elem(ya[k], yb[k], f[k], r[k], oa[k], ob[k]);

        #pragma unroll
        for (int k = 0; k < ITERS; ++k) {
            int e = e0 + k * stride;
            __builtin_nontemporal_store(oa[k], out4 + 2 * e);
            __builtin_nontemporal_store(ob[k], out4 + 2 * e + 1);
        }
    } else {
        // ---- tail path: boundary block only ----
        for (int k = 0; k < ITERS; ++k) {
            int e = e0 + k * stride;
            if (e < B) {
                v4f ya = __builtin_nontemporal_load(y4 + 2 * e);
                v4f yb = __builtin_nontemporal_load(y4 + 2 * e + 1);
                v4f f  = __builtin_nontemporal_load(kf4 + e);
                v4f r  = __builtin_nontemporal_load(kr4 + e);
                v4f oa, ob;
                ode_elem(ya, yb, f, r, oa, ob);
                __builtin_nontemporal_store(oa, out4 + 2 * e);
                __builtin_nontemporal_store(ob, out4 + 2 * e + 1);
            }
        }
    }
}

extern "C" void kernel_launch(void* const* d_in, const int* in_sizes, int n_in,
                              void* d_out, int out_size, void* d_ws, size_t ws_size,
                              hipStream_t stream) {
    // inputs: [0]=t (1,), [1]=y (B,8), [2]=forward_rates (B,4), [3]=reverse_rates (B,4)
    const v4f* y4  = (const v4f*)d_in[1];
    const v4f* kf4 = (const v4f*)d_in[2];
    const v4f* kr4 = (const v4f*)d_in[3];
    v4f* out4 = (v4f*)d_out;
    int B = in_sizes[1] / 8;

    int block = 256;
    int grid  = (B + block * ITERS - 1) / (block * ITERS);
    ode_kernel<<<grid, block, 0, stream>>>(y4, kf4, kr4, out4, B);
}

// Round 6
// 164.599 us; speedup vs baseline: 1.0653x; 1.0226x over previous
//
#include <hip/hip_runtime.h>

// Ordered bi-bi mechanism dydt. Species: [E, EA, EQ, EAB, A, B, P, Q].
//
// ONE THREAD PER ELEMENT, no cross-lane exchange (R5 proved the 8-swizzle
// vmcnt->lgkmcnt chain was the hidden serializer: removing it went 60->43us,
// 2.1->3.4 TB/s).
//
// R6 changes vs R5:
//  1. Stores are REGULAR (cached), not nontemporal. R5's nt stores at 32B
//     lane stride half-covered 64B lines and bypassed L2 write-merging ->
//     WRITE_SIZE 62.5->82 MB (+31% write amplification). Cached stores merge
//     in L2 (R2 measured exactly 62.5 MB with identical coverage).
//  2. ITERS 2->4: 16 independent nt loads (256B) in flight per thread to
//     raise memory-level parallelism toward the 6.3 TB/s copy ceiling.
// Loads keep the nt hint (FETCH_SIZE identical with/without; streaming reads
// need no L2 retention).

typedef float v4f __attribute__((ext_vector_type(4)));

#define ITERS 4

__device__ __forceinline__ void ode_elem(v4f ya, v4f yb, v4f f, v4f r,
                                         v4f& oa, v4f& ob) {
    float E  = ya.x, EA = ya.y, EQ = ya.z, EAB = ya.w;
    float A  = yb.x, Bc = yb.y, P  = yb.z, Q   = yb.w;

    float v0 = f.x * E   * A  - r.x * EA;
    float v1 = f.y * EA  * Bc - r.y * EAB;
    float v2 = f.z * EAB      - r.z * EQ * P;
    float v3 = f.w * EQ       - r.w * E  * Q;

    oa.x = v3 - v0;   // dE
    oa.y = v0 - v1;   // dEA
    oa.z = v2 - v3;   // dEQ
    oa.w = v1 - v2;   // dEAB
    ob.x = -v0;       // dA
    ob.y = -v1;       // dB
    ob.z =  v2;       // dP
    ob.w =  v3;       // dQ
}

__global__ __launch_bounds__(256) void ode_kernel(
    const v4f* __restrict__ y4,
    const v4f* __restrict__ kf4,
    const v4f* __restrict__ kr4,
    v4f* __restrict__ out4,
    int B)    // number of elements
{
    const int stride = gridDim.x * blockDim.x;
    const int e0 = blockIdx.x * blockDim.x + threadIdx.x;

    if (e0 + (ITERS - 1) * stride < B) {
        // ---- fast path: branch-free. all loads -> compute -> all stores ----
        v4f ya[ITERS], yb[ITERS], f[ITERS], r[ITERS];
        #pragma unroll
        for (int k = 0; k < ITERS; ++k) {
            int e = e0 + k * stride;
            ya[k] = __builtin_nontemporal_load(y4 + 2 * e);
            yb[k] = __builtin_nontemporal_load(y4 + 2 * e + 1);
            f[k]  = __builtin_nontemporal_load(kf4 + e);
            r[k]  = __builtin_nontemporal_load(kr4 + e);
        }

        v4f oa[ITERS], ob[ITERS];
        #pragma unroll
        for (int k = 0; k < ITERS; ++k)
            ode_elem(ya[k], yb[k], f[k], r[k], oa[k], ob[k]);

        #pragma unroll
        for (int k = 0; k < ITERS; ++k) {
            int e = e0 + k * stride;
            out4[2 * e]     = oa[k];   // cached: L2 merges the half-line pairs
            out4[2 * e + 1] = ob[k];
        }
    } else {
        // ---- tail path: boundary block only ----
        for (int k = 0; k < ITERS; ++k) {
            int e = e0 + k * stride;
            if (e < B) {
                v4f ya = __builtin_nontemporal_load(y4 + 2 * e);
                v4f yb = __builtin_nontemporal_load(y4 + 2 * e + 1);
                v4f f  = __builtin_nontemporal_load(kf4 + e);
                v4f r  = __builtin_nontemporal_load(kr4 + e);
                v4f oa, ob;
                ode_elem(ya, yb, f, r, oa, ob);
                out4[2 * e]     = oa;
                out4[2 * e + 1] = ob;
            }
        }
    }
}

extern "C" void kernel_launch(void* const* d_in, const int* in_sizes, int n_in,
                              void* d_out, int out_size, void* d_ws, size_t ws_size,
                              hipStream_t stream) {
    // inputs: [0]=t (1,), [1]=y (B,8), [2]=forward_rates (B,4), [3]=reverse_rates (B,4)
    const v4f* y4  = (const v4f*)d_in[1];
    const v4f* kf4 = (const v4f*)d_in[2];
    const v4f* kr4 = (const v4f*)d_in[3];
    v4f* out4 = (v4f*)d_out;
    int B = in_sizes[1] / 8;

    int block = 256;
    int grid  = (B + block * ITERS - 1) / (block * ITERS);
    ode_kernel<<<grid, block, 0, stream>>>(y4, kf4, kr4, out4, B);
}